// Round 9
// baseline (134.802 us; speedup 1.0000x reference)
//
#include <hip/hip_runtime.h>
#include <hip/hip_cooperative_groups.h>

// QuantumDMRGLayer: B=2048, L=196, M=16, NBL=10, pos_label=98 (fixed by setup).
// Round-16: r8 (dual-chain wave) regressed +17us: interleave gained ~10%
// per-work but halved wave count. Chain micro-structure is at a local
// optimum -> keep r5's chain VERBATIM (85.4us best).
// New lever: budget calibration (r4 chain=60.4 in 124.9 total) shows a
// constant ~17-19us of inter-dispatch gap time across all rounds (4 serial
// dispatches in the timed window). v16 merges prep+chain+out into ONE
// cooperative kernel (grid.sync between phases; harness-supported):
//   phase 1: prep_pair body on blocks 0..96 (r5 verbatim)
//   phase 2: r5 chain on wave 0 of each of the 128 blocks (identical mapping)
//   phase 3: out_kernel body spread over 128 blocks x 256 thr
// Zero arithmetic change -> absmax must stay bit-identical (6.94e-18).

namespace cg = cooperative_groups;

typedef __attribute__((ext_vector_type(8))) short short8;
typedef __attribute__((ext_vector_type(16))) float floatx16;

#define PSET_DW 512                    // dwords per MFMA-set (hi 256 | lo 256)
#define PAIR_DW (2 * PSET_DW)          // 2 sets per pair-step
#define LSTEPS 49                      // left: 98 sites = 49 pairs
#define RSTEPS 48                      // right: 96 sites = 48 pairs
#define RBASE_DW (LSTEPS * PAIR_DW)    // right stream base
#define WST_OFF_DW ((LSTEPS + RSTEPS) * PAIR_DW)   // states after streams
// WS: pair streams 97*4KB = 388KB, then WST [dir][2048][16] floats (256KB)

__device__ __forceinline__ unsigned bf16_rne(unsigned u) {
    return (u + 0x7FFFu + ((u >> 16) & 1u)) >> 16;
}

// r0-verified split-bf16 pack
#define PACK(W, VH, VL)                                                      \
    {                                                                        \
        _Pragma("unroll")                                                    \
        for (int q = 0; q < 4; ++q) {                                        \
            const unsigned u0 = __float_as_uint(W[2 * q]);                   \
            const unsigned u1 = __float_as_uint(W[2 * q + 1]);               \
            const unsigned h0 = u0 & 0xFFFF0000u, h1 = u1 & 0xFFFF0000u;     \
            const float l0 = W[2 * q]     - __uint_as_float(h0);             \
            const float l1 = W[2 * q + 1] - __uint_as_float(h1);             \
            ((unsigned*)&VH)[q] = h1 | (h0 >> 16);                           \
            ((unsigned*)&VL)[q] = (__float_as_uint(l1) & 0xFFFF0000u) |      \
                                  (__float_as_uint(l0) >> 16);               \
        }                                                                    \
    }

__global__ __launch_bounds__(256, 1)
void mega_kernel(const float* __restrict__ X,
                 const float* __restrict__ AL,
                 const float* __restrict__ AR,
                 const float* __restrict__ AM,
                 const float* __restrict__ T,
                 unsigned* __restrict__ WS,
                 float* __restrict__ WST,
                 float* __restrict__ OUT)
{
    cg::grid_group grid = cg::this_grid();

    __shared__ float sA0[2][16][16];
    __shared__ float sA1[2][16][16];
    __shared__ float sT[2560];

    const int tid = threadIdx.x;
    const int bid = blockIdx.x;                // 0..127

    // ================= phase 1: prep_pair (r5 verbatim, blocks 0..96) ====
    if (bid < 97) {
        const int dir = (bid >= LSTEPS) ? 1 : 0;
        const int t   = dir ? (bid - LSTEPS) : bid;
        const int a0  = dir ? (192 - 2 * t) : (2 * t);
        const int a1  = a0 + 1;

        for (int i = tid; i < 512; i += 256) {
            ((float*)sA0)[i] = AM[a0 * 512 + i];
            ((float*)sA1)[i] = AM[a1 * 512 + i];
        }
        __syncthreads();

        unsigned* gp = WS + (dir ? (RBASE_DW + t * PAIR_DW) : (t * PAIR_DW));
        for (int u = tid; u < 512; u += 256) { // 2 sets x 64 lanes x 4 dwords
            const int s_   = u >> 8;
            const int lane = (u & 255) >> 2;
            const int w_   = u & 3;
            const int r    = lane & 31;
            const int kb   = (lane >> 5) << 3;
            const int d    = r >> 4;
            const int rl   = r & 15;
            const int sig  = (rl & 3) | ((rl & 4) << 1) | ((rl & 8) >> 1); // pi
            const int b0 = s_, b1 = d;
            const int k0 = kb + 2 * w_;
            float q0 = 0.f, q1 = 0.f;
            if (dir == 0) {
#pragma unroll
                for (int m_ = 0; m_ < 16; ++m_) {
                    const float a1v = sA1[b1][m_][sig];
                    q0 = fmaf(sA0[b0][k0][m_],     a1v, q0);
                    q1 = fmaf(sA0[b0][k0 + 1][m_], a1v, q1);
                }
            } else {
#pragma unroll
                for (int m_ = 0; m_ < 16; ++m_) {
                    const float a0v = sA0[b0][sig][m_];
                    q0 = fmaf(a0v, sA1[b1][m_][k0],     q0);
                    q1 = fmaf(a0v, sA1[b1][m_][k0 + 1], q1);
                }
            }
            const unsigned u0 = __float_as_uint(q0), u1 = __float_as_uint(q1);
            const unsigned h0 = bf16_rne(u0), h1 = bf16_rne(u1);
            const float l0f = q0 - __uint_as_float(h0 << 16);
            const float l1f = q1 - __uint_as_float(h1 << 16);
            const unsigned lo0 = bf16_rne(__float_as_uint(l0f));
            const unsigned lo1 = bf16_rne(__float_as_uint(l1f));
            gp[s_ * PSET_DW + lane * 4 + w_]       = (h1 << 16) | h0;
            gp[s_ * PSET_DW + 256 + lane * 4 + w_] = (lo1 << 16) | lo0;
        }
    }

    grid.sync();

    // ================= phase 2: chain (r5 verbatim, wave 0 per block) ====
    if (tid < 64) {
        const int lane = tid;                  // 0..63
        const int dir  = bid & 1;
        const int s    = (bid >> 1) * 32 + (lane & 31);
        const int kb   = (lane >> 5) << 3;     // this lane's k-half base
        const float* Xs = X + s * 392;
        const unsigned* Gb = WS + (dir ? RBASE_DW : 0) + lane * 4;
        const int nsteps = dir ? RSTEPS : LSTEPS;

        float w[8];
        int4 vh4, vl4;

        // ---- init bond vector ----
        const float* Ai = dir ? AR : AL;
        const float2 xi = *(const float2*)(Xs + (dir ? 390 : 0));
#pragma unroll
        for (int j = 0; j < 8; ++j)
            w[j] = xi.x * Ai[kb + j] + xi.y * Ai[16 + kb + j];
        PACK(w, vh4, vl4);

        const floatx16 Z = {};                 // persistent zero C (hoisted)

        // ---- 2-slot register ring, STATIC indexing via unroll-2 ----
        int4 GH0[2], GL0[2], GH1[2], GL1[2];
        float2 xp[2], xq[2];
        {
            const unsigned* gp0 = Gb;
            GH0[0] = *(const int4*)(gp0);
            GL0[0] = *(const int4*)(gp0 + 256);
            GH1[0] = *(const int4*)(gp0 + PSET_DW);
            GL1[0] = *(const int4*)(gp0 + PSET_DW + 256);
            const int xo0 = dir ? 386 : 2;
            xp[0] = *(const float2*)(Xs + xo0);
            xq[0] = *(const float2*)(Xs + xo0 + 2);
            const unsigned* gp1 = Gb + PAIR_DW;
            GH0[1] = *(const int4*)(gp1);
            GL0[1] = *(const int4*)(gp1 + 256);
            GH1[1] = *(const int4*)(gp1 + PSET_DW);
            GL1[1] = *(const int4*)(gp1 + PSET_DW + 256);
            const int xo1 = dir ? 382 : 6;
            xp[1] = *(const float2*)(Xs + xo1);
            xq[1] = *(const float2*)(Xs + xo1 + 2);
        }

        for (int c = 0; c < 25; ++c) {
#pragma unroll
            for (int half = 0; half < 2; ++half) { // slot = half: static
                const int t = 2 * c + half;
                if (t < nsteps) {
                    const short8 ah0 = *(const short8*)&GH0[half];
                    const short8 al0 = *(const short8*)&GL0[half];
                    const short8 ah1 = *(const short8*)&GH1[half];
                    const short8 al1 = *(const short8*)&GL1[half];
                    const float2 xpc = xp[half], xqc = xq[half];

                    const int tn = (t + 2 < nsteps) ? (t + 2) : t;
                    const unsigned* gp = Gb + tn * PAIR_DW;
                    GH0[half] = *(const int4*)(gp);
                    GL0[half] = *(const int4*)(gp + 256);
                    GH1[half] = *(const int4*)(gp + PSET_DW);
                    GL1[half] = *(const int4*)(gp + PSET_DW + 256);
                    const int xo = dir ? (386 - 4 * tn) : (4 * tn + 2);
                    xp[half] = *(const float2*)(Xs + xo);
                    xq[half] = *(const float2*)(Xs + xo + 2);

                    const short8 bh = *(const short8*)&vh4;
                    const short8 bl = *(const short8*)&vl4;
                    floatx16 D0, D1;
                    D0 = __builtin_amdgcn_mfma_f32_32x32x16_bf16(ah0, bh, Z,  0, 0, 0);
                    D1 = __builtin_amdgcn_mfma_f32_32x32x16_bf16(ah1, bh, Z,  0, 0, 0);
                    D0 = __builtin_amdgcn_mfma_f32_32x32x16_bf16(ah0, bl, D0, 0, 0, 0);
                    D1 = __builtin_amdgcn_mfma_f32_32x32x16_bf16(ah1, bl, D1, 0, 0, 0);
                    D0 = __builtin_amdgcn_mfma_f32_32x32x16_bf16(al0, bh, D0, 0, 0, 0);
                    D1 = __builtin_amdgcn_mfma_f32_32x32x16_bf16(al1, bh, D1, 0, 0, 0);

                    const float c0 = xpc.x * xqc.x, c1 = xpc.x * xqc.y;
                    const float c2 = xpc.y * xqc.x, c3 = xpc.y * xqc.y;
#pragma unroll
                    for (int j = 0; j < 8; ++j)
                        w[j] = fmaf(c0, D0[j],
                               fmaf(c1, D0[j + 8],
                               fmaf(c2, D1[j], c3 * D1[j + 8])));
                    PACK(w, vh4, vl4);
                }
            }
        }

        // ---- final state (fp32): comps kb..kb+7 of sample s ----
        float* st = WST + (dir * 2048 + s) * 16 + kb;
        *(float4*)(st)     = make_float4(w[0], w[1], w[2], w[3]);
        *(float4*)(st + 4) = make_float4(w[4], w[5], w[6], w[7]);
    }

    // stage T into LDS while waiting (read-only input, no hazard with WST)
    for (int k = tid; k < 640; k += 256)
        ((float4*)sT)[k] = ((const float4*)T)[k];

    grid.sync();

    // ================= phase 3: out (r5 body over 128 blocks) ============
    {
        const int t = bid * 256 + tid;         // < 32768, need < 20480
        if (t < 20480) {
            const int s = t / 10, l = t - s * 10;
            const float* L = WST + s * 16;
            const float* R = WST + 2048 * 16 + s * 16;
            const float4 Ra = *(const float4*)(R);
            const float4 Rb = *(const float4*)(R + 4);
            const float4 Rc = *(const float4*)(R + 8);
            const float4 Rd = *(const float4*)(R + 12);
            float acc = 0.f;
#pragma unroll
            for (int m = 0; m < 16; ++m) {
                const float lm = L[m];
                const float* Tp = sT + m * 160 + l;
                acc = fmaf(lm * Ra.x, Tp[0],   acc);
                acc = fmaf(lm * Ra.y, Tp[10],  acc);
                acc = fmaf(lm * Ra.z, Tp[20],  acc);
                acc = fmaf(lm * Ra.w, Tp[30],  acc);
                acc = fmaf(lm * Rb.x, Tp[40],  acc);
                acc = fmaf(lm * Rb.y, Tp[50],  acc);
                acc = fmaf(lm * Rb.z, Tp[60],  acc);
                acc = fmaf(lm * Rb.w, Tp[70],  acc);
                acc = fmaf(lm * Rc.x, Tp[80],  acc);
                acc = fmaf(lm * Rc.y, Tp[90],  acc);
                acc = fmaf(lm * Rc.z, Tp[100], acc);
                acc = fmaf(lm * Rc.w, Tp[110], acc);
                acc = fmaf(lm * Rd.x, Tp[120], acc);
                acc = fmaf(lm * Rd.y, Tp[130], acc);
                acc = fmaf(lm * Rd.z, Tp[140], acc);
                acc = fmaf(lm * Rd.w, Tp[150], acc);
            }
            OUT[t] = acc;
        }
    }
}

extern "C" void kernel_launch(void* const* d_in, const int* in_sizes, int n_in,
                              void* d_out, int out_size, void* d_ws, size_t ws_size,
                              hipStream_t stream)
{
    const float* X  = (const float*)d_in[0];   // (2048,196,2)
    const float* AL = (const float*)d_in[1];   // (2,16)
    const float* AM = (const float*)d_in[2];   // (194,2,16,16)
    const float* AR = (const float*)d_in[3];   // (2,16)
    const float* T  = (const float*)d_in[4];   // (16,16,10)
    (void)in_sizes; (void)n_in; (void)out_size; (void)ws_size;
    unsigned* WS = (unsigned*)d_ws;            // pair streams: 388 KB
    float* WST   = (float*)d_ws + WST_OFF_DW;  // states: 256 KB
    float* OUT   = (float*)d_out;              // (2048,10)

    void* kargs[] = { (void*)&X, (void*)&AL, (void*)&AR, (void*)&AM,
                      (void*)&T, (void*)&WS, (void*)&WST, (void*)&OUT };
    hipLaunchCooperativeKernel((const void*)mega_kernel,
                               dim3(128), dim3(256), kargs, 0, stream);
}

// Round 10
// 87.960 us; speedup vs baseline: 1.5325x; 1.5325x over previous
//
#include <hip/hip_runtime.h>

// QuantumDMRGLayer: B=2048, L=196, M=16, NBL=10, pos_label=98 (fixed by setup).
// Round-17: r9 (coop mega) falsified the launch-gap theory (+25us coop
// overhead, 50us mega). Recalibration across r0/r5/r8 (fill 40.3 + harness
// restores ~18.6 fixed): per-MFMA cost ~160-200cyc regardless of chain
// structure; independent MFMAs DON'T fill the stall (r8). Hypothesis: the
// per-iteration stall is a SHARED conservative s_waitcnt vmcnt(0) on the
// prefetch ring -> every step eats L2 latency once, all chains together.
// v17 = r5 with the G-path decoupled from vmcnt:
//   - 8-slot LDS ring (32KB) filled by global_load_lds (width 16), staged
//     7 steps ahead of use.
//   - per step: EXPLICIT counted s_waitcnt vmcnt(6) (only last iter's 6 VMEM
//     ops may be outstanding; the slot read was staged ~7 steps earlier)
//     + sched_barrier(0), then 4x ds_read_b128 into a static 2-slot register
//     ring, then r5's VERBATIM 6-MFMA / combine / pack.
//   - tail refills re-stage step nsteps-1 into its own slot (idempotent).
// prep_pair / out_kernel / all arithmetic verbatim from the passing r5.

typedef __attribute__((ext_vector_type(8))) short short8;
typedef __attribute__((ext_vector_type(16))) float floatx16;

#define PSET_DW 512                    // dwords per MFMA-set (hi 256 | lo 256)
#define PAIR_DW (2 * PSET_DW)          // 2 sets per pair-step
#define LSTEPS 49                      // left: 98 sites = 49 pairs
#define RSTEPS 48                      // right: 96 sites = 48 pairs
#define RBASE_DW (LSTEPS * PAIR_DW)    // right stream base
#define WST_OFF_DW ((LSTEPS + RSTEPS) * PAIR_DW)   // states after streams
// WS: pair streams 97*4KB = 388KB, then WST [dir][2048][16] floats (256KB)

__device__ __forceinline__ unsigned bf16_rne(unsigned u) {
    return (u + 0x7FFFu + ((u >> 16) & 1u)) >> 16;
}

// ---- prep: per site-pair, 4 fp32 combo products -> split-bf16 G sets ----
// (verbatim from r4/r5, harness-verified)
__global__ __launch_bounds__(256)
void prep_pair(const float* __restrict__ AM, unsigned* __restrict__ WS)
{
    __shared__ float sA0[2][16][16];
    __shared__ float sA1[2][16][16];
    const int pidx = blockIdx.x;               // 0..96
    const int tid  = threadIdx.x;
    const int dir  = (pidx >= LSTEPS) ? 1 : 0;
    const int t    = dir ? (pidx - LSTEPS) : pidx;
    const int a0   = dir ? (192 - 2 * t) : (2 * t);
    const int a1   = a0 + 1;

    for (int i = tid; i < 512; i += 256) {
        ((float*)sA0)[i] = AM[a0 * 512 + i];
        ((float*)sA1)[i] = AM[a1 * 512 + i];
    }
    __syncthreads();

    unsigned* gp = WS + (dir ? (RBASE_DW + t * PAIR_DW) : (t * PAIR_DW));
    for (int u = tid; u < 512; u += 256) {     // 2 sets x 64 lanes x 4 dwords
        const int s_   = u >> 8;
        const int lane = (u & 255) >> 2;
        const int w_   = u & 3;
        const int r    = lane & 31;
        const int kb   = (lane >> 5) << 3;
        const int d    = r >> 4;
        const int rl   = r & 15;
        const int sig  = (rl & 3) | ((rl & 4) << 1) | ((rl & 8) >> 1);  // pi
        const int b0 = s_, b1 = d;
        const int k0 = kb + 2 * w_;
        float q0 = 0.f, q1 = 0.f;
        if (dir == 0) {
#pragma unroll
            for (int m_ = 0; m_ < 16; ++m_) {
                const float a1v = sA1[b1][m_][sig];
                q0 = fmaf(sA0[b0][k0][m_],     a1v, q0);
                q1 = fmaf(sA0[b0][k0 + 1][m_], a1v, q1);
            }
        } else {
#pragma unroll
            for (int m_ = 0; m_ < 16; ++m_) {
                const float a0v = sA0[b0][sig][m_];
                q0 = fmaf(a0v, sA1[b1][m_][k0],     q0);
                q1 = fmaf(a0v, sA1[b1][m_][k0 + 1], q1);
            }
        }
        const unsigned u0 = __float_as_uint(q0), u1 = __float_as_uint(q1);
        const unsigned h0 = bf16_rne(u0), h1 = bf16_rne(u1);
        const float l0f = q0 - __uint_as_float(h0 << 16);
        const float l1f = q1 - __uint_as_float(h1 << 16);
        const unsigned lo0 = bf16_rne(__float_as_uint(l0f));
        const unsigned lo1 = bf16_rne(__float_as_uint(l1f));
        gp[s_ * PSET_DW + lane * 4 + w_]       = (h1 << 16) | h0;
        gp[s_ * PSET_DW + 256 + lane * 4 + w_] = (lo1 << 16) | lo0;
    }
}

// r0-verified split-bf16 pack
#define PACK(W, VH, VL)                                                      \
    {                                                                        \
        _Pragma("unroll")                                                    \
        for (int q = 0; q < 4; ++q) {                                        \
            const unsigned u0 = __float_as_uint(W[2 * q]);                   \
            const unsigned u1 = __float_as_uint(W[2 * q + 1]);               \
            const unsigned h0 = u0 & 0xFFFF0000u, h1 = u1 & 0xFFFF0000u;     \
            const float l0 = W[2 * q]     - __uint_as_float(h0);             \
            const float l1 = W[2 * q + 1] - __uint_as_float(h1);             \
            ((unsigned*)&VH)[q] = h1 | (h0 >> 16);                           \
            ((unsigned*)&VL)[q] = (__float_as_uint(l1) & 0xFFFF0000u) |      \
                                  (__float_as_uint(l0) >> 16);               \
        }                                                                    \
    }

// global -> LDS direct copy, 16B per lane (wave-uniform LDS base)
__device__ __forceinline__ void gload_lds16(const unsigned* g, unsigned* l)
{
    __builtin_amdgcn_global_load_lds(
        (const __attribute__((address_space(1))) unsigned*)g,
        (__attribute__((address_space(3))) unsigned*)l, 16, 0, 0);
}

// ---- main chain: 1 wave = 32 samples x 1 direction, pair steps ----
// G staged through an 8-slot LDS ring, 7+ steps ahead; counted vmcnt(6).
__global__ __launch_bounds__(64, 1)
void chain_kernel(const float* __restrict__ X,
                  const float* __restrict__ AL,
                  const float* __restrict__ AR,
                  const unsigned* __restrict__ WS,
                  float* __restrict__ WST)
{
    __shared__ unsigned sG[8 * 1024] __attribute__((aligned(16)));  // 32 KB

    const int lane = threadIdx.x;              // 0..63
    const int dir  = blockIdx.x & 1;
    const int s    = (blockIdx.x >> 1) * 32 + (lane & 31);
    const int kb   = (lane >> 5) << 3;         // this lane's k-half base
    const float* Xs = X + s * 392;
    const unsigned* Gdir = WS + (dir ? RBASE_DW : 0);
    const int nsteps = dir ? RSTEPS : LSTEPS;

    // stage step tn into LDS slot tn&7 (4 x 1KB chunks, lane*16B each)
    auto stage = [&](int tn) {
        const unsigned* gsb = Gdir + tn * PAIR_DW + lane * 4;
        unsigned* lds = sG + (tn & 7) * 1024;
        gload_lds16(gsb,       lds);
        gload_lds16(gsb + 256, lds + 256);
        gload_lds16(gsb + 512, lds + 512);
        gload_lds16(gsb + 768, lds + 768);
    };

    // ---- prologue: fill all 8 slots (steps 0..7; nsteps >= 48) ----
#pragma unroll
    for (int i = 0; i < 8; ++i) stage(i);
    __builtin_amdgcn_s_waitcnt(0x0F70);        // vmcnt(0)
    __builtin_amdgcn_sched_barrier(0);

    // ---- init bond vector (verbatim r0/r5) ----
    float w[8];
    int4 vh4, vl4;
    {
        const float* Ai = dir ? AR : AL;
        const float2 xi = *(const float2*)(Xs + (dir ? 390 : 0));
#pragma unroll
        for (int j = 0; j < 8; ++j)
            w[j] = xi.x * Ai[kb + j] + xi.y * Ai[16 + kb + j];
        PACK(w, vh4, vl4);
    }

    const floatx16 Z = {};                     // persistent zero C (hoisted)

    // ---- register ring (2 slots, static via unroll-2) primed with step 0 ----
    int4 GH0r[2], GL0r[2], GH1r[2], GL1r[2];
    {
        const int4* sp = (const int4*)(sG);
        GH0r[0] = sp[lane];
        GL0r[0] = sp[64 + lane];
        GH1r[0] = sp[128 + lane];
        GL1r[0] = sp[192 + lane];
    }
    // X ring: steps 0,1 (r5 verbatim offsets)
    float2 xp[2], xq[2];
    {
        const int xo0 = dir ? 386 : 2;
        xp[0] = *(const float2*)(Xs + xo0);
        xq[0] = *(const float2*)(Xs + xo0 + 2);
        const int xo1 = dir ? 382 : 6;
        xp[1] = *(const float2*)(Xs + xo1);
        xq[1] = *(const float2*)(Xs + xo1 + 2);
    }

    for (int c = 0; c < 25; ++c) {
#pragma unroll
        for (int half = 0; half < 2; ++half) { // ring index: compile-time
            const int t = 2 * c + half;
            // (a) counted wait: slot (t+1)&7 was staged >=7 iters ago;
            //     only last iter's 6 VMEM ops (4 stage + 2 X) may be pending
            __builtin_amdgcn_s_waitcnt(0x0F76);   // vmcnt(6)
            __builtin_amdgcn_sched_barrier(0);
            // (b) ds_read step t+1 into ring[half^1]
            {
                const int4* sp = (const int4*)(sG + ((t + 1) & 7) * 1024);
                GH0r[half ^ 1] = sp[lane];
                GL0r[half ^ 1] = sp[64 + lane];
                GH1r[half ^ 1] = sp[128 + lane];
                GL1r[half ^ 1] = sp[192 + lane];
            }
            // (c,d) compute step t (r5 verbatim arithmetic)
            if (t < nsteps) {
                const short8 ah0 = *(const short8*)&GH0r[half];
                const short8 al0 = *(const short8*)&GL0r[half];
                const short8 ah1 = *(const short8*)&GH1r[half];
                const short8 al1 = *(const short8*)&GL1r[half];
                const float2 xpc = xp[half], xqc = xq[half];

                const short8 bh = *(const short8*)&vh4;
                const short8 bl = *(const short8*)&vl4;
                floatx16 D0, D1;
                D0 = __builtin_amdgcn_mfma_f32_32x32x16_bf16(ah0, bh, Z,  0, 0, 0);
                D1 = __builtin_amdgcn_mfma_f32_32x32x16_bf16(ah1, bh, Z,  0, 0, 0);
                D0 = __builtin_amdgcn_mfma_f32_32x32x16_bf16(ah0, bl, D0, 0, 0, 0);
                D1 = __builtin_amdgcn_mfma_f32_32x32x16_bf16(ah1, bl, D1, 0, 0, 0);
                D0 = __builtin_amdgcn_mfma_f32_32x32x16_bf16(al0, bh, D0, 0, 0, 0);
                D1 = __builtin_amdgcn_mfma_f32_32x32x16_bf16(al1, bh, D1, 0, 0, 0);

                const float c0 = xpc.x * xqc.x, c1 = xpc.x * xqc.y;
                const float c2 = xpc.y * xqc.x, c3 = xpc.y * xqc.y;
#pragma unroll
                for (int j = 0; j < 8; ++j)
                    w[j] = fmaf(c0, D0[j],
                           fmaf(c1, D0[j + 8],
                           fmaf(c2, D1[j], c3 * D1[j + 8])));
                PACK(w, vh4, vl4);

                // X refill for step t+2 (r5 verbatim, clamped)
                const int tn = (t + 2 < nsteps) ? (t + 2) : t;
                const int xo = dir ? (386 - 4 * tn) : (4 * tn + 2);
                xp[half] = *(const float2*)(Xs + xo);
                xq[half] = *(const float2*)(Xs + xo + 2);
            }
            // (e) refill G ring: step t+8 (tail: re-stage nsteps-1, its own
            //     slot, identical bytes -> idempotent, race-free)
            const int tn8 = (t + 8 < nsteps) ? (t + 8) : (nsteps - 1);
            stage(tn8);
        }
    }

    // ---- final state (fp32): comps kb..kb+7 of sample s (verbatim r0) ----
    float* st = WST + (dir * 2048 + s) * 16 + kb;
    *(float4*)(st)     = make_float4(w[0], w[1], w[2], w[3]);
    *(float4*)(st + 4) = make_float4(w[4], w[5], w[6], w[7]);
}

// ---- epilogue: out[s,l] = sum_{m,n} L[m,s] T[m,n,l] R[n,s] (verbatim r0) ----
__global__ __launch_bounds__(256)
void out_kernel(const float* __restrict__ T, const float* __restrict__ WST,
                float* __restrict__ OUT)
{
    __shared__ float sT[2560];
    const int tid = threadIdx.x;
    for (int k = tid; k < 640; k += 256)
        ((float4*)sT)[k] = ((const float4*)T)[k];
    __syncthreads();
    const int t = blockIdx.x * 256 + tid;      // < 20480
    const int s = t / 10, l = t - s * 10;
    const float* L = WST + s * 16;
    const float* R = WST + 2048 * 16 + s * 16;
    const float4 Ra = *(const float4*)(R);
    const float4 Rb = *(const float4*)(R + 4);
    const float4 Rc = *(const float4*)(R + 8);
    const float4 Rd = *(const float4*)(R + 12);
    float acc = 0.f;
#pragma unroll
    for (int m = 0; m < 16; ++m) {
        const float lm = L[m];
        const float* Tp = sT + m * 160 + l;
        acc = fmaf(lm * Ra.x, Tp[0],   acc);
        acc = fmaf(lm * Ra.y, Tp[10],  acc);
        acc = fmaf(lm * Ra.z, Tp[20],  acc);
        acc = fmaf(lm * Ra.w, Tp[30],  acc);
        acc = fmaf(lm * Rb.x, Tp[40],  acc);
        acc = fmaf(lm * Rb.y, Tp[50],  acc);
        acc = fmaf(lm * Rb.z, Tp[60],  acc);
        acc = fmaf(lm * Rb.w, Tp[70],  acc);
        acc = fmaf(lm * Rc.x, Tp[80],  acc);
        acc = fmaf(lm * Rc.y, Tp[90],  acc);
        acc = fmaf(lm * Rc.z, Tp[100], acc);
        acc = fmaf(lm * Rc.w, Tp[110], acc);
        acc = fmaf(lm * Rd.x, Tp[120], acc);
        acc = fmaf(lm * Rd.y, Tp[130], acc);
        acc = fmaf(lm * Rd.z, Tp[140], acc);
        acc = fmaf(lm * Rd.w, Tp[150], acc);
    }
    OUT[t] = acc;
}

extern "C" void kernel_launch(void* const* d_in, const int* in_sizes, int n_in,
                              void* d_out, int out_size, void* d_ws, size_t ws_size,
                              hipStream_t stream)
{
    const float* X  = (const float*)d_in[0];   // (2048,196,2)
    const float* AL = (const float*)d_in[1];   // (2,16)
    const float* AM = (const float*)d_in[2];   // (194,2,16,16)
    const float* AR = (const float*)d_in[3];   // (2,16)
    const float* T  = (const float*)d_in[4];   // (16,16,10)
    (void)in_sizes; (void)n_in; (void)out_size; (void)ws_size;
    unsigned* WS = (unsigned*)d_ws;            // pair streams: 388 KB
    float* WST   = (float*)d_ws + WST_OFF_DW;  // states: 256 KB
    float* OUT   = (float*)d_out;              // (2048,10)

    hipLaunchKernelGGL(prep_pair,    dim3(97),  dim3(256), 0, stream, AM, WS);
    hipLaunchKernelGGL(chain_kernel, dim3(128), dim3(64),  0, stream,
                       X, AL, AR, WS, WST);
    hipLaunchKernelGGL(out_kernel,   dim3(80),  dim3(256), 0, stream,
                       T, WST, OUT);
}

// Round 12
// 85.655 us; speedup vs baseline: 1.5738x; 1.0269x over previous
//
#include <hip/hip_runtime.h>

// QuantumDMRGLayer: B=2048, L=196, M=16, NBL=10, pos_label=98 (fixed by setup).
// FINAL (round-19): exact resubmission of the verified best (r5 / v12,
// 85.4us, absmax 6.94e-18). Session findings:
//   - chain time ~= MFMA_count x ~170cyc at 1 wave/SIMD, invariant to chain
//     depth (r6: unchaining regressed), accumulator independence (r8),
//     G source / prefetch discipline (r10: LDS ring + counted vmcnt neutral),
//     and step grouping (r0->r5 pair-steps won only the step-overhead ~11%).
//   - occupancy/TLP levers: basis-split (r1-r3) inflates work 16x, net loss;
//     coop mega-kernel (r9) +25us overhead; 512-thread TLP variant (r11)
//     miscompiles numerically (1.7e-15 vs 3.3e-17) with an identical step
//     body -- codegen-level, unexplained, twice burned.
//   - remaining budget: ~59us harness-fixed (40us d_ws poison fill + ~19us
//     restore dispatches) + ~26.5us compute (prep 3.5 + chain 21 + out 2).
// v12 structure: pair-site steps (prep computes 4 fp32 combo products
// Q_ab = A_a,p * A_b,p+1 per pair; one chain step = 2 sites, 2 MFMA-sets,
// coeffs x_a,p*x_b,p+1), chained 3-MFMA split-bf16 per set, static unroll-2
// register ring, 128 waves x 32 samples.

typedef __attribute__((ext_vector_type(8))) short short8;
typedef __attribute__((ext_vector_type(16))) float floatx16;

#define PSET_DW 512                    // dwords per MFMA-set (hi 256 | lo 256)
#define PAIR_DW (2 * PSET_DW)          // 2 sets per pair-step
#define LSTEPS 49                      // left: 98 sites = 49 pairs
#define RSTEPS 48                      // right: 96 sites = 48 pairs
#define RBASE_DW (LSTEPS * PAIR_DW)    // right stream base
#define WST_OFF_DW ((LSTEPS + RSTEPS) * PAIR_DW)   // states after streams
// WS: pair streams 97*4KB = 388KB, then WST [dir][2048][16] floats (256KB)

__device__ __forceinline__ unsigned bf16_rne(unsigned u) {
    return (u + 0x7FFFu + ((u >> 16) & 1u)) >> 16;
}

// ---- prep: per site-pair, 4 fp32 combo products -> split-bf16 G sets ----
// (verbatim from r4, harness-verified)
__global__ __launch_bounds__(256)
void prep_pair(const float* __restrict__ AM, unsigned* __restrict__ WS)
{
    __shared__ float sA0[2][16][16];
    __shared__ float sA1[2][16][16];
    const int pidx = blockIdx.x;               // 0..96
    const int tid  = threadIdx.x;
    const int dir  = (pidx >= LSTEPS) ? 1 : 0;
    const int t    = dir ? (pidx - LSTEPS) : pidx;
    const int a0   = dir ? (192 - 2 * t) : (2 * t);
    const int a1   = a0 + 1;

    for (int i = tid; i < 512; i += 256) {
        ((float*)sA0)[i] = AM[a0 * 512 + i];
        ((float*)sA1)[i] = AM[a1 * 512 + i];
    }
    __syncthreads();

    unsigned* gp = WS + (dir ? (RBASE_DW + t * PAIR_DW) : (t * PAIR_DW));
    for (int u = tid; u < 512; u += 256) {     // 2 sets x 64 lanes x 4 dwords
        const int s_   = u >> 8;
        const int lane = (u & 255) >> 2;
        const int w_   = u & 3;
        const int r    = lane & 31;
        const int kb   = (lane >> 5) << 3;
        const int d    = r >> 4;
        const int rl   = r & 15;
        const int sig  = (rl & 3) | ((rl & 4) << 1) | ((rl & 8) >> 1);  // pi
        const int b0 = s_, b1 = d;
        const int k0 = kb + 2 * w_;
        float q0 = 0.f, q1 = 0.f;
        if (dir == 0) {
#pragma unroll
            for (int m_ = 0; m_ < 16; ++m_) {
                const float a1v = sA1[b1][m_][sig];
                q0 = fmaf(sA0[b0][k0][m_],     a1v, q0);
                q1 = fmaf(sA0[b0][k0 + 1][m_], a1v, q1);
            }
        } else {
#pragma unroll
            for (int m_ = 0; m_ < 16; ++m_) {
                const float a0v = sA0[b0][sig][m_];
                q0 = fmaf(a0v, sA1[b1][m_][k0],     q0);
                q1 = fmaf(a0v, sA1[b1][m_][k0 + 1], q1);
            }
        }
        const unsigned u0 = __float_as_uint(q0), u1 = __float_as_uint(q1);
        const unsigned h0 = bf16_rne(u0), h1 = bf16_rne(u1);
        const float l0f = q0 - __uint_as_float(h0 << 16);
        const float l1f = q1 - __uint_as_float(h1 << 16);
        const unsigned lo0 = bf16_rne(__float_as_uint(l0f));
        const unsigned lo1 = bf16_rne(__float_as_uint(l1f));
        gp[s_ * PSET_DW + lane * 4 + w_]       = (h1 << 16) | h0;
        gp[s_ * PSET_DW + 256 + lane * 4 + w_] = (lo1 << 16) | lo0;
    }
}

// ---- main chain: 1 wave = 32 samples x 1 direction, pair steps ----
__global__ __launch_bounds__(64, 1)
void chain_kernel(const float* __restrict__ X,
                  const float* __restrict__ AL,
                  const float* __restrict__ AR,
                  const unsigned* __restrict__ WS,
                  float* __restrict__ WST)
{
    const int lane = threadIdx.x;              // 0..63
    const int dir  = blockIdx.x & 1;
    const int s    = (blockIdx.x >> 1) * 32 + (lane & 31);
    const int kb   = (lane >> 5) << 3;         // this lane's k-half base
    const float* Xs = X + s * 392;
    const unsigned* Gb = WS + (dir ? RBASE_DW : 0) + lane * 4;
    const int nsteps = dir ? RSTEPS : LSTEPS;

    // split fp32 comps -> packed bf16 hi/lo fragments (r0-verified pack)
    float w[8];
    int4 vh4, vl4;
    auto pack = [&]() {
#pragma unroll
        for (int q = 0; q < 4; ++q) {
            const unsigned u0 = __float_as_uint(w[2 * q]);
            const unsigned u1 = __float_as_uint(w[2 * q + 1]);
            const unsigned h0 = u0 & 0xFFFF0000u, h1 = u1 & 0xFFFF0000u;
            const float l0 = w[2 * q]     - __uint_as_float(h0);
            const float l1 = w[2 * q + 1] - __uint_as_float(h1);
            ((unsigned*)&vh4)[q] = h1 | (h0 >> 16);
            ((unsigned*)&vl4)[q] = (__float_as_uint(l1) & 0xFFFF0000u) |
                                   (__float_as_uint(l0) >> 16);
        }
    };

    // ---- init bond vector (verbatim r0) ----
    const float* Ai = dir ? AR : AL;
    const float2 xi = *(const float2*)(Xs + (dir ? 390 : 0));
#pragma unroll
    for (int j = 0; j < 8; ++j)
        w[j] = xi.x * Ai[kb + j] + xi.y * Ai[16 + kb + j];
    pack();

    const floatx16 Z = {};                     // persistent zero C (hoisted)

    // ---- 2-slot register ring, STATIC indexing via unroll-2 ----
    int4 GH0[2], GL0[2], GH1[2], GL1[2];       // [slot] x set0/set1
    float2 xp[2], xq[2];
    {
        const unsigned* gp0 = Gb;
        GH0[0] = *(const int4*)(gp0);
        GL0[0] = *(const int4*)(gp0 + 256);
        GH1[0] = *(const int4*)(gp0 + PSET_DW);
        GL1[0] = *(const int4*)(gp0 + PSET_DW + 256);
        const int xo0 = dir ? 386 : 2;
        xp[0] = *(const float2*)(Xs + xo0);
        xq[0] = *(const float2*)(Xs + xo0 + 2);
        const unsigned* gp1 = Gb + PAIR_DW;
        GH0[1] = *(const int4*)(gp1);
        GL0[1] = *(const int4*)(gp1 + 256);
        GH1[1] = *(const int4*)(gp1 + PSET_DW);
        GL1[1] = *(const int4*)(gp1 + PSET_DW + 256);
        const int xo1 = dir ? 382 : 6;
        xp[1] = *(const float2*)(Xs + xo1);
        xq[1] = *(const float2*)(Xs + xo1 + 2);
    }

    for (int c = 0; c < 25; ++c) {
#pragma unroll
        for (int half = 0; half < 2; ++half) { // slot = half: compile-time
            const int t = 2 * c + half;
            if (t < nsteps) {
                const short8 ah0 = *(const short8*)&GH0[half];
                const short8 al0 = *(const short8*)&GL0[half];
                const short8 ah1 = *(const short8*)&GH1[half];
                const short8 al1 = *(const short8*)&GL1[half];
                const float2 xpc = xp[half], xqc = xq[half];

                // prefetch step t+2 into this slot (operands copied above)
                const int tn = (t + 2 < nsteps) ? (t + 2) : t;
                const unsigned* gp = Gb + tn * PAIR_DW;
                GH0[half] = *(const int4*)(gp);
                GL0[half] = *(const int4*)(gp + 256);
                GH1[half] = *(const int4*)(gp + PSET_DW);
                GL1[half] = *(const int4*)(gp + PSET_DW + 256);
                const int xo = dir ? (386 - 4 * tn) : (4 * tn + 2);
                xp[half] = *(const float2*)(Xs + xo);
                xq[half] = *(const float2*)(Xs + xo + 2);

                const short8 bh = *(const short8*)&vh4;
                const short8 bl = *(const short8*)&vl4;
                // two independent 3-MFMA chains, interleaved issue
                floatx16 D0, D1;
                D0 = __builtin_amdgcn_mfma_f32_32x32x16_bf16(ah0, bh, Z,  0, 0, 0);
                D1 = __builtin_amdgcn_mfma_f32_32x32x16_bf16(ah1, bh, Z,  0, 0, 0);
                D0 = __builtin_amdgcn_mfma_f32_32x32x16_bf16(ah0, bl, D0, 0, 0, 0);
                D1 = __builtin_amdgcn_mfma_f32_32x32x16_bf16(ah1, bl, D1, 0, 0, 0);
                D0 = __builtin_amdgcn_mfma_f32_32x32x16_bf16(al0, bh, D0, 0, 0, 0);
                D1 = __builtin_amdgcn_mfma_f32_32x32x16_bf16(al1, bh, D1, 0, 0, 0);

                // c_{2*b0+b1} = x_{b0}(first site) * x_{b1}(second site)
                const float c0 = xpc.x * xqc.x, c1 = xpc.x * xqc.y;
                const float c2 = xpc.y * xqc.x, c3 = xpc.y * xqc.y;
#pragma unroll
                for (int j = 0; j < 8; ++j)
                    w[j] = fmaf(c0, D0[j],
                           fmaf(c1, D0[j + 8],
                           fmaf(c2, D1[j], c3 * D1[j + 8])));
                pack();
            }
        }
    }

    // ---- final state (fp32): comps kb..kb+7 of sample s (verbatim r0) ----
    float* st = WST + (dir * 2048 + s) * 16 + kb;
    *(float4*)(st)     = make_float4(w[0], w[1], w[2], w[3]);
    *(float4*)(st + 4) = make_float4(w[4], w[5], w[6], w[7]);
}

// ---- epilogue: out[s,l] = sum_{m,n} L[m,s] T[m,n,l] R[n,s] (verbatim r0) ----
__global__ __launch_bounds__(256)
void out_kernel(const float* __restrict__ T, const float* __restrict__ WST,
                float* __restrict__ OUT)
{
    __shared__ float sT[2560];
    const int tid = threadIdx.x;
    for (int k = tid; k < 640; k += 256)
        ((float4*)sT)[k] = ((const float4*)T)[k];
    __syncthreads();
    const int t = blockIdx.x * 256 + tid;      // < 20480
    const int s = t / 10, l = t - s * 10;
    const float* L = WST + s * 16;
    const float* R = WST + 2048 * 16 + s * 16;
    const float4 Ra = *(const float4*)(R);
    const float4 Rb = *(const float4*)(R + 4);
    const float4 Rc = *(const float4*)(R + 8);
    const float4 Rd = *(const float4*)(R + 12);
    float acc = 0.f;
#pragma unroll
    for (int m = 0; m < 16; ++m) {
        const float lm = L[m];
        const float* Tp = sT + m * 160 + l;
        acc = fmaf(lm * Ra.x, Tp[0],   acc);
        acc = fmaf(lm * Ra.y, Tp[10],  acc);
        acc = fmaf(lm * Ra.z, Tp[20],  acc);
        acc = fmaf(lm * Ra.w, Tp[30],  acc);
        acc = fmaf(lm * Rb.x, Tp[40],  acc);
        acc = fmaf(lm * Rb.y, Tp[50],  acc);
        acc = fmaf(lm * Rb.z, Tp[60],  acc);
        acc = fmaf(lm * Rb.w, Tp[70],  acc);
        acc = fmaf(lm * Rc.x, Tp[80],  acc);
        acc = fmaf(lm * Rc.y, Tp[90],  acc);
        acc = fmaf(lm * Rc.z, Tp[100], acc);
        acc = fmaf(lm * Rc.w, Tp[110], acc);
        acc = fmaf(lm * Rd.x, Tp[120], acc);
        acc = fmaf(lm * Rd.y, Tp[130], acc);
        acc = fmaf(lm * Rd.z, Tp[140], acc);
        acc = fmaf(lm * Rd.w, Tp[150], acc);
    }
    OUT[t] = acc;
}

extern "C" void kernel_launch(void* const* d_in, const int* in_sizes, int n_in,
                              void* d_out, int out_size, void* d_ws, size_t ws_size,
                              hipStream_t stream)
{
    const float* X  = (const float*)d_in[0];   // (2048,196,2)
    const float* AL = (const float*)d_in[1];   // (2,16)
    const float* AM = (const float*)d_in[2];   // (194,2,16,16)
    const float* AR = (const float*)d_in[3];   // (2,16)
    const float* T  = (const float*)d_in[4];   // (16,16,10)
    (void)in_sizes; (void)n_in; (void)out_size; (void)ws_size;
    unsigned* WS = (unsigned*)d_ws;            // pair streams: 388 KB
    float* WST   = (float*)d_ws + WST_OFF_DW;  // states: 256 KB
    float* OUT   = (float*)d_out;              // (2048,10)

    hipLaunchKernelGGL(prep_pair,    dim3(97),  dim3(256), 0, stream, AM, WS);
    hipLaunchKernelGGL(chain_kernel, dim3(128), dim3(64),  0, stream,
                       X, AL, AR, WS, WST);
    hipLaunchKernelGGL(out_kernel,   dim3(80),  dim3(256), 0, stream,
                       T, WST, OUT);
}